// Round 19
// baseline (180.238 us; speedup 1.0000x reference)
//
#include <hip/hip_runtime.h>
#include <math.h>

// Problem constants
// x: (16,64,3,32,32) x2 concat -> (1024,6,32,32)
// conv1 6->64 k3 p1 -> BN -> ReLU -> pool2 -> (1024,64,16,16)
// conv2 64->64 k3 p1 -> BN -> ReLU -> pool2 -> (1024,64,8,8) = feats (1024,4096)
// RNN T=64 steps over feats rows n=b*64+t ; head -> sigmoid (16,1)
//
// R19: RNN reverted to R15 (77us; R17/R18 wave-packing spilled -> regressed).
// preq_reduce DELETED: its 8-way partial sum + Qb bias fused into rnn_head's
// pq staging loop. preq split-K 16->8 (partials 7.3->3.7MB). Rest = R16.

typedef __attribute__((ext_vector_type(8))) short s8v;   // 8 bf16 (4 VGPRs)
typedef __attribute__((ext_vector_type(4))) float f32x4;

__device__ __forceinline__ unsigned short f2bf(float f) {
  union { float f; unsigned u; } x; x.f = f;
  return (unsigned short)((x.u + 0x7FFFu + ((x.u >> 16) & 1u)) >> 16);  // RNE
}
__device__ __forceinline__ float bf2f(unsigned short u) {
  union { unsigned u; float f; } x; x.u = ((unsigned)u) << 16; return x.f;
}
// fast tanh: 1 - 2/(e^{2x}+1); inf-safe via rcp (e=inf -> 0 -> +1; e->0 -> -1)
__device__ __forceinline__ float ftanh(float x) {
  float e = __expf(2.f * x);
  return 1.f - 2.f * __builtin_amdgcn_rcpf(e + 1.f);
}

// ---------------------------------------------------------------------------
// pack_all: w1 -> bf16 [kh][64co][32k] (k=kw*6+ci, zero pad k>=18);
//           w2 -> bf16 [khw][co][ci] with ci-chunk XOR swizzle;
//           Qw[:, :4096] -> bf16 [112][4096] (rows >=100 zero).
// ---------------------------------------------------------------------------
__global__ __launch_bounds__(256)
void pack_all(const float* __restrict__ w1, const float* __restrict__ w2,
              const float* __restrict__ Qw,
              unsigned short* __restrict__ wB1, unsigned short* __restrict__ wB2,
              unsigned short* __restrict__ qB)
{
  int i = blockIdx.x*256 + threadIdx.x;   // 6144 + 36864 + 458752 = 501760
  if (i < 6144) {
    int kh = i >> 11, rem = i & 2047, co = rem >> 5, k2 = rem & 31;
    unsigned short v = 0;
    if (k2 < 18) {
      int kw = k2 / 6, ci = k2 - 6*kw;
      v = f2bf(w1[co*54 + ci*9 + kh*3 + kw]);
    }
    wB1[i] = v;
  } else if (i < 43008) {
    int j = i - 6144;
    int khw = j >> 12, rem = j & 4095, co = rem >> 6, ci = rem & 63;
    int chunk = (ci >> 3) ^ (co & 7);
    wB2[khw*4096 + co*64 + chunk*8 + (ci & 7)] = f2bf(w2[co*576 + ci*9 + khw]);
  } else if (i < 501760) {
    int j = i - 43008;
    int row = j >> 12, k = j & 4095;
    qB[j] = (row < 100) ? f2bf(Qw[row*4196 + k]) : (unsigned short)0;
  }
}

// ---------------------------------------------------------------------------
// conv1 via MFMA implicit GEMM, computed ONCE. grid 1024, block 256 (4 waves).
// Epilogue stores ONE pooled value per (pixel, channel): max if gamma1>=0
// else min (sign(bn scale) == sign(gamma)).
// ---------------------------------------------------------------------------
__global__ __launch_bounds__(256, 4)
void conv1_mfma(const float* __restrict__ x1, const float* __restrict__ x2,
                const unsigned short* __restrict__ wB1,
                const float* __restrict__ bn1g,
                float* __restrict__ part, unsigned short* __restrict__ pool1s)
{
  __shared__ unsigned xin[3688];          // 34 rows x 108 dwords + 16 pad
  __shared__ float wred[4][4][16][2];
  __shared__ float gsel[64];
  const int n = blockIdx.x, tid = threadIdx.x;
  const int w = tid >> 6, lane = tid & 63;
  const int q = lane >> 4, r = lane & 15;

  if (tid < 64) gsel[tid] = bn1g[tid];

  // B fragments, whole kernel in regs: bf[kh][t], co = 16t + r, k0 = 8q
  s8v bf[3][4];
  #pragma unroll
  for (int kh = 0; kh < 3; ++kh)
    #pragma unroll
    for (int t = 0; t < 4; ++t)
      bf[kh][t] = *(const s8v*)&wB1[kh*2048 + (((t<<4)+r)<<5) + (q<<3)];

  // zero ALL of xin (incl. pad tail) -- overread garbage must be finite
  #pragma unroll
  for (int k = 0; k < 15; ++k) {
    int i = tid + (k<<8);
    if (i < 3688) xin[i] = 0;
  }
  __syncthreads();
  // interior fill: dword (y+1)*108 + (x+1)*3 + cp packs bf16{ci=2cp,2cp+1}
  #pragma unroll
  for (int k = 0; k < 12; ++k) {
    int i = tid + (k<<8);     // 0..3071
    int cp = i >> 10, p = i & 1023;
    int y = p >> 5, x = p & 31;
    float lo, hi;
    if (cp == 0)      { lo = x1[n*3072 + p];        hi = x1[n*3072 + 1024 + p]; }
    else if (cp == 1) { lo = x1[n*3072 + 2048 + p]; hi = x2[n*3072 + p];        }
    else              { lo = x2[n*3072 + 1024 + p]; hi = x2[n*3072 + 2048 + p]; }
    xin[(y+1)*108 + (x+1)*3 + cp] = (unsigned)f2bf(lo) | ((unsigned)f2bf(hi) << 16);
  }
  __syncthreads();

  float st[4], sq[4];
  #pragma unroll
  for (int t = 0; t < 4; ++t) { st[t] = 0.f; sq[t] = 0.f; }
  float pmx[4][2], pmn[4][2];

  #pragma unroll 1
  for (int xb = 0; xb < 2; ++xb) {
    const int xbase = xb << 4;
    #pragma unroll 2
    for (int j = 0; j < 8; ++j) {           // y = 8w + j
      const int y = (w << 3) + j;
      f32x4 acc[4];
      #pragma unroll
      for (int t = 0; t < 4; ++t) acc[t] = (f32x4){0.f,0.f,0.f,0.f};
      #pragma unroll
      for (int kh = 0; kh < 3; ++kh) {      // k-step == kh slice
        int dw = (y + kh)*108 + 3*(xbase + r) + (q << 2);
        union { unsigned u[4]; s8v v; } af;
        af.u[0] = xin[dw];   af.u[1] = xin[dw+1];
        af.u[2] = xin[dw+2]; af.u[3] = xin[dw+3];
        #pragma unroll
        for (int t = 0; t < 4; ++t)
          acc[t] = __builtin_amdgcn_mfma_f32_16x16x32_bf16(af.v, bf[kh][t], acc[t], 0, 0, 0);
      }
      #pragma unroll
      for (int t = 0; t < 4; ++t) {
        st[t] += acc[t][0]+acc[t][1]+acc[t][2]+acc[t][3];
        sq[t] = fmaf(acc[t][0],acc[t][0], fmaf(acc[t][1],acc[t][1],
                fmaf(acc[t][2],acc[t][2], fmaf(acc[t][3],acc[t][3], sq[t]))));
      }
      if ((j & 1) == 0) {                   // even y: stash x-pair max/min
        #pragma unroll
        for (int t = 0; t < 4; ++t) {
          pmx[t][0] = fmaxf(acc[t][0], acc[t][1]); pmx[t][1] = fmaxf(acc[t][2], acc[t][3]);
          pmn[t][0] = fminf(acc[t][0], acc[t][1]); pmn[t][1] = fminf(acc[t][2], acc[t][3]);
        }
      } else {                              // odd y: combine + write pooled sel
        const int py = y >> 1;
        #pragma unroll
        for (int t = 0; t < 4; ++t) {
          int co = (t << 4) + r;
          const bool useMax = (gsel[co] >= 0.f);
          #pragma unroll
          for (int pp = 0; pp < 2; ++pp) {
            float mx = fmaxf(pmx[t][pp], fmaxf(acc[t][2*pp], acc[t][2*pp+1]));
            float mn = fminf(pmn[t][pp], fminf(acc[t][2*pp], acc[t][2*pp+1]));
            int pxp = (xb << 3) + (q << 1) + pp;
            int o = (((n << 8) + (py << 4) + pxp) << 6) + co;
            pool1s[o] = f2bf(useMax ? mx : mn);
          }
        }
      }
    }
  }

  #pragma unroll
  for (int t = 0; t < 4; ++t) {
    float s = st[t], ss = sq[t];
    s  += __shfl_xor(s, 16);  s  += __shfl_xor(s, 32);
    ss += __shfl_xor(ss, 16); ss += __shfl_xor(ss, 32);
    if (q == 0) { wred[w][t][r][0] = s; wred[w][t][r][1] = ss; }
  }
  __syncthreads();
  if (tid < 64) {
    float s = 0.f, ss = 0.f;
    #pragma unroll
    for (int wv = 0; wv < 4; ++wv) {
      s  += wred[wv][tid >> 4][tid & 15][0];
      ss += wred[wv][tid >> 4][tid & 15][1];
    }
    part[tid*2048 + n*2]     = s;     // layout [c][n][2]
    part[tid*2048 + n*2 + 1] = ss;
  }
}

// ---------------------------------------------------------------------------
// BN finalize: per-channel mean/var -> scale/shift.  grid 64, block 256.
// ---------------------------------------------------------------------------
__global__ __launch_bounds__(256)
void bn_finalize(const float* __restrict__ part, const float* __restrict__ g,
                 const float* __restrict__ beta, float inv_cnt, float* __restrict__ bn)
{
  __shared__ float red[8];
  const int c = blockIdx.x, tid = threadIdx.x;
  float s = 0.f, ss = 0.f;
  for (int n = tid; n < 1024; n += 256) {
    s  += part[c*2048 + n*2];
    ss += part[c*2048 + n*2 + 1];
  }
  #pragma unroll
  for (int d = 32; d; d >>= 1) { s += __shfl_xor(s, d); ss += __shfl_xor(ss, d); }
  if ((tid & 63) == 0) { red[(tid>>6)*2] = s; red[(tid>>6)*2+1] = ss; }
  __syncthreads();
  if (tid == 0) {
    float S  = red[0]+red[2]+red[4]+red[6];
    float SS = red[1]+red[3]+red[5]+red[7];
    float m  = S * inv_cnt;
    float var = SS * inv_cnt - m*m;
    float sc = g[c] * rsqrtf(var + 1e-5f);
    bn[c]    = sc;
    bn[64+c] = beta[c] - m*sc;
  }
}

// ---------------------------------------------------------------------------
// conv2 via MFMA implicit GEMM. grid 1024 (one image), block 256 (4 waves).
// Staging fuses conv1 BN affine + ReLU reading the single pool1s array.
// Epilogue stores single pooled sel per channel via sign(gamma2).
// ---------------------------------------------------------------------------
__global__ __launch_bounds__(256)
void conv2_mfma(const unsigned short* __restrict__ pool1s,
                const float* __restrict__ bn1,
                const float* __restrict__ bn2g,
                const unsigned short* __restrict__ wB,
                float* __restrict__ part, unsigned short* __restrict__ psel2)
{
  __shared__ unsigned short xin[324*64];   // 41472 B
  __shared__ unsigned short wL[9*64*64];   // 73728 B
  __shared__ float wred[4][4][16][2];      // 2 KB
  __shared__ float bnL[128];
  __shared__ float g2L[64];
  const int n = blockIdx.x, tid = threadIdx.x;
  const int w = tid >> 6, lane = tid & 63;
  const int q = lane >> 4, col = lane & 15;

  if (tid < 128) bnL[tid] = bn1[tid];
  if (tid >= 128 && tid < 192) g2L[tid - 128] = bn2g[tid - 128];
  // ---- stage weights (linear copy; swizzle pre-applied in pack) ----
  {
    const s8v* src = (const s8v*)wB;
    s8v* dst = (s8v*)wL;
    #pragma unroll
    for (int i = 0; i < 18; ++i) dst[tid + (i<<8)] = src[tid + (i<<8)];
  }
  __syncthreads();   // bnL/g2L ready
  // ---- stage input 18x18x64 bf16 = relu(affine(pool1s)), halo zeros,
  //      swizzled 16B chunks ----
  {
    #pragma unroll
    for (int k = 0; k < 11; ++k) {
      int i = tid + (k<<8);
      if (i < 324*8) {
        int L = i >> 3, s = i & 7;
        int y = L / 18, x = L - y*18;
        s8v v = (s8v){0,0,0,0,0,0,0,0};
        if (y >= 1 && y <= 16 && x >= 1 && x <= 16) {
          int idx = (((n<<8) + ((y-1)<<4) + (x-1))<<6) + (s<<3);
          s8v sv = *(const s8v*)&pool1s[idx];
          #pragma unroll
          for (int e = 0; e < 8; ++e) {
            int ci = (s<<3) + e;
            float sc = bnL[ci], sh = bnL[64+ci];
            float vv = bf2f((unsigned short)sv[e]);
            v[e] = (short)f2bf(fmaxf(fmaf(vv, sc, sh), 0.f));
          }
        }
        *(s8v*)((char*)xin + L*128 + (((s ^ (L & 7)) << 4))) = v;
      }
    }
  }
  __syncthreads();

  f32x4 acc[4][4];   // [mtile][ntile]
  #pragma unroll
  for (int mt = 0; mt < 4; ++mt)
    #pragma unroll
    for (int t = 0; t < 4; ++t)
      acc[mt][t] = (f32x4){0.f,0.f,0.f,0.f};

  const int py0 = w << 2;   // wave's 4 image rows
  #pragma unroll 1
  for (int khw = 0; khw < 9; ++khw) {
    const int kh = khw / 3, kw = khw - 3*kh;
    const char* wslice = (const char*)wL + khw*8192;
    #pragma unroll
    for (int ks = 0; ks < 2; ++ks) {       // ci0 = 32*ks
      const int chunk = (ks << 2) + q;     // 16B-chunk of k within line
      s8v bfrag[4];
      #pragma unroll
      for (int t = 0; t < 4; ++t) {
        int co = (t << 4) + col;
        bfrag[t] = *(const s8v*)(wslice + co*128 + (((chunk ^ (co & 7)) << 4)));
      }
      #pragma unroll
      for (int mt = 0; mt < 4; ++mt) {
        int L = (py0 + mt + kh)*18 + (col + kw);
        s8v afrag = *(const s8v*)((const char*)xin + L*128 + (((chunk ^ (L & 7)) << 4)));
        #pragma unroll
        for (int t = 0; t < 4; ++t)
          acc[mt][t] = __builtin_amdgcn_mfma_f32_16x16x32_bf16(afrag, bfrag[t], acc[mt][t], 0, 0, 0);
      }
    }
  }

  // ---- stats: per-channel sum / sumsq over this block's 256 pixels ----
  #pragma unroll
  for (int t = 0; t < 4; ++t) {
    float s = 0.f, ss = 0.f;
    #pragma unroll
    for (int mt = 0; mt < 4; ++mt)
      #pragma unroll
      for (int r = 0; r < 4; ++r) {
        float v = acc[mt][t][r];
        s += v; ss = fmaf(v, v, ss);
      }
    s  += __shfl_xor(s, 16);  s  += __shfl_xor(s, 32);
    ss += __shfl_xor(ss, 16); ss += __shfl_xor(ss, 32);
    if (q == 0) { wred[w][t][col][0] = s; wred[w][t][col][1] = ss; }
  }
  __syncthreads();
  if (tid < 64) {
    float s = 0.f, ss = 0.f;
    #pragma unroll
    for (int wv = 0; wv < 4; ++wv) {
      s  += wred[wv][tid >> 4][tid & 15][0];
      ss += wred[wv][tid >> 4][tid & 15][1];
    }
    part[tid*2048 + n*2]     = s;
    part[tid*2048 + n*2 + 1] = ss;
  }

  // ---- 2x2 pooled sel (max if gamma2>=0 else min) of raw conv, bf16 ----
  #pragma unroll
  for (int t = 0; t < 4; ++t) {
    int co = (t << 4) + col;
    const bool useMax = (g2L[co] >= 0.f);
    #pragma unroll
    for (int mp = 0; mp < 2; ++mp) {          // vertical pair (rows 2mp,2mp+1)
      f32x4 a0 = acc[2*mp][t], a1 = acc[2*mp+1][t];
      float v0, v1;
      if (useMax) {
        v0 = fmaxf(fmaxf(a0[0], a0[1]), fmaxf(a1[0], a1[1]));
        v1 = fmaxf(fmaxf(a0[2], a0[3]), fmaxf(a1[2], a1[3]));
      } else {
        v0 = fminf(fminf(a0[0], a0[1]), fminf(a1[0], a1[1]));
        v1 = fminf(fminf(a0[2], a0[3]), fminf(a1[2], a1[3]));
      }
      int pyp = (w << 1) + mp;                // pooled y
      int base = ((n*64 + co) << 6) + (pyp << 3) + (q << 1);  // feats c*64+p
      psel2[base] = f2bf(v0); psel2[base+1] = f2bf(v1);
    }
  }
}

// ---------------------------------------------------------------------------
// preQ partials via MFMA, fusing conv2's BN affine + ReLU into the A-frag
// load. No LDS. grid (16 mblocks x 8 ksplits) -- R19: split-K halved, K=512
// per block (16 k-steps). part layout [ks][1024][112] fp32, ks < 8.
// ---------------------------------------------------------------------------
__global__ __launch_bounds__(256)
void preq_mfma(const unsigned short* __restrict__ psel2,
               const float* __restrict__ bn2,
               const unsigned short* __restrict__ qB,
               float* __restrict__ part)
{
  const int mb = blockIdx.x, ks = blockIdx.y, tid = threadIdx.x;
  const int w = tid >> 6, lane = tid & 63;
  const int q = lane >> 4, col = lane & 15;
  const int m = (mb << 6) + (w << 4) + col;    // A row this lane loads
  const int k00 = ks << 9;                     // 512 per ks

  f32x4 acc[7];
  #pragma unroll
  for (int t = 0; t < 7; ++t) acc[t] = (f32x4){0.f,0.f,0.f,0.f};

  #pragma unroll 2
  for (int kk = 0; kk < 16; ++kk) {
    const int k = k00 + (kk << 5) + (q << 3);  // 8-aligned, one c per chunk
    const int c = k >> 6;
    const float sc = bn2[c], sh = bn2[64 + c];
    s8v sv = *(const s8v*)&psel2[m*4096 + k];
    s8v a;
    #pragma unroll
    for (int e = 0; e < 8; ++e)
      a[e] = (short)f2bf(fmaxf(fmaf(bf2f((unsigned short)sv[e]), sc, sh), 0.f));
    #pragma unroll
    for (int t = 0; t < 7; ++t) {
      s8v bb = *(const s8v*)&qB[(((t << 4) + col) << 12) + k];
      acc[t] = __builtin_amdgcn_mfma_f32_16x16x32_bf16(a, bb, acc[t], 0, 0, 0);
    }
  }

  // C: col=lane&15 = j16, row=4q+r = m-row within the wave's 16-row tile
  float* dst = part + ks*114688 + ((mb << 6) + (w << 4) + (q << 2))*112;
  #pragma unroll
  for (int t = 0; t < 7; ++t)
    #pragma unroll
    for (int r = 0; r < 4; ++r)
      dst[r*112 + (t << 4) + col] = acc[t][r];
}

// ---------------------------------------------------------------------------
// RNN (64 sequential steps) + head. grid 16 (one block per batch b), block 512.
// R15 structure (measured 77us floor). R19: pq staging FUSES the preq partial
// reduction (8-way sum over part[ks][n][112] + Qb bias) -- preq_reduce kernel
// deleted.
// ---------------------------------------------------------------------------
__global__ __launch_bounds__(512, 2)
void rnn_head(const float* __restrict__ part, const float* __restrict__ Qb,
              const float* __restrict__ Rw,
              const float* __restrict__ Rb, const float* __restrict__ Qw,
              const float* __restrict__ Ow, const float* __restrict__ Ob,
              const float* __restrict__ f1w, const float* __restrict__ f1b,
              const float* __restrict__ f2w, const float* __restrict__ f2b,
              float* __restrict__ out)
{
  __shared__ __align__(16) float ha[400];
  __shared__ __align__(16) float rtP[112];   // 4 quarters x 28 (pads zero)
  __shared__ float pq[6400];
  __shared__ float rb[100];
  __shared__ __align__(16) float ol[128];
  __shared__ float f1[64];
  const int b = blockIdx.x, tid = threadIdx.x;

  // pq[t*100+j] = Qb[j] + sum_ks part[ks][(b*64+t)*112 + j]
  for (int i = tid; i < 6400; i += 512) {
    int t = i / 100, j = i - t*100;
    int base = (b*64 + t)*112 + j;
    float s = Qb[j];
    #pragma unroll
    for (int ks = 0; ks < 8; ++ks) s += part[ks*114688 + base];
    pq[i] = s;
  }
  if (tid < 100) rb[tid] = Rb[tid];
  if (tid < 400) ha[tid] = 0.f;
  if (tid < 112) rtP[tid] = 0.f;             // pads stay zero forever

  const int o = tid >> 2, q4 = tid & 3;
  const int rtSlot = (o / 25)*28 + (o % 25);
  float rw[100], qw[28];
  if (tid < 400) {
    const float* rsrc = &Rw[o*400 + q4*100];
    #pragma unroll
    for (int i = 0; i < 25; ++i) {
      float4 v = *(const float4*)&rsrc[i*4];
      rw[i*4] = v.x; rw[i*4+1] = v.y; rw[i*4+2] = v.z; rw[i*4+3] = v.w;
    }
    const float* qsrc = &Qw[o*4196 + 4096 + q4*25];
    #pragma unroll
    for (int i = 0; i < 25; ++i) qw[i] = qsrc[i];
    qw[25] = 0.f; qw[26] = 0.f; qw[27] = 0.f;   // multiply rtP pads
  }
  const float Aa = (q4==0) ? 0.f : (q4==1) ? 0.25f : (q4==2) ? 0.5f : 0.95f;
  const float Ba = 1.f - Aa;
  float haReg = 0.f;
  __syncthreads();

  for (int t = 0; t < 64; ++t) {
    if (tid < 400) {
      float r0 = 0.f, r1 = 0.f, r2 = 0.f, r3 = 0.f;
      const float* hp = &ha[q4*100];
      #pragma unroll
      for (int i = 0; i < 25; i += 4) {
        float4 a0 = *(const float4*)&hp[i*4];
        float4 a1 = *(const float4*)&hp[i*4+4];
        float4 a2 = *(const float4*)&hp[i*4+8];
        float4 a3 = *(const float4*)&hp[i*4+12];
        r0 = fmaf(rw[i*4],    a0.x, r0); r0 = fmaf(rw[i*4+1],  a0.y, r0);
        r0 = fmaf(rw[i*4+2],  a0.z, r0); r0 = fmaf(rw[i*4+3],  a0.w, r0);
        if (i+1 < 25) {
          r1 = fmaf(rw[i*4+4],  a1.x, r1); r1 = fmaf(rw[i*4+5],  a1.y, r1);
          r1 = fmaf(rw[i*4+6],  a1.z, r1); r1 = fmaf(rw[i*4+7],  a1.w, r1);
        }
        if (i+2 < 25) {
          r2 = fmaf(rw[i*4+8],  a2.x, r2); r2 = fmaf(rw[i*4+9],  a2.y, r2);
          r2 = fmaf(rw[i*4+10], a2.z, r2); r2 = fmaf(rw[i*4+11], a2.w, r2);
        }
        if (i+3 < 25) {
          r3 = fmaf(rw[i*4+12], a3.x, r3); r3 = fmaf(rw[i*4+13], a3.y, r3);
          r3 = fmaf(rw[i*4+14], a3.z, r3); r3 = fmaf(rw[i*4+15], a3.w, r3);
        }
      }
      float racc = (r0 + r1) + (r2 + r3);
      racc += __shfl_xor(racc, 1);
      racc += __shfl_xor(racc, 2);
      if (q4 == 0) rtP[rtSlot] = ftanh(racc + rb[o]);
    }
    __syncthreads();
    if (tid < 400) {
      float s0 = 0.f, s1 = 0.f;
      const float* rp = &rtP[q4*28];
      #pragma unroll
      for (int i = 0; i < 7; i += 2) {
        float4 v0 = *(const float4*)&rp[i*4];
        s0 = fmaf(qw[i*4],   v0.x, s0); s0 = fmaf(qw[i*4+1], v0.y, s0);
        s0 = fmaf(qw[i*4+2], v0.z, s0); s0 = fmaf(qw[i*4+3], v0.w, s0);
        if (i+1 < 7) {
          float4 v1 = *(const float4*)&rp[i*4+4];
          s1 = fmaf(qw[i*4+4], v1.x, s1); s1 = fmaf(qw[i*4+5], v1.y, s1);
          s1 = fmaf(qw[i*4+6], v1.z, s1); s1 = fmaf(qw[i*4+7], v1.w, s1);
        }
      }
      float qacc = s0 + s1;
      qacc += __shfl_xor(qacc, 1);
      qacc += __shfl_xor(qacc, 2);
      float qt = ftanh(qacc + pq[t*100 + o]);
      haReg = fmaf(Aa, haReg, Ba*qt);
      ha[q4*100 + o] = haReg;           // write-through for next R-phase
    }
    __syncthreads();
  }

  // head: out_last = tanh(Hf @ Ow^T + Ob), 2 threads per output
  if (tid < 256) {
    const int j2 = tid >> 1, hh = tid & 1;
    const float* osrc = &Ow[j2*400 + hh*200];
    const float* hp = &ha[hh*200];
    float oacc = 0.f;
    #pragma unroll
    for (int i = 0; i < 50; ++i) {
      float4 w4 = *(const float4*)&osrc[i*4];
      float4 h4 = *(const float4*)&hp[i*4];
      oacc = fmaf(w4.x, h4.x, oacc); oacc = fmaf(w4.y, h4.y, oacc);
      oacc = fmaf(w4.z, h4.z, oacc); oacc = fmaf(w4.w, h4.w, oacc);
    }
    oacc += __shfl_xor(oacc, 1);
    if (hh == 0) ol[j2] = ftanh(oacc + Ob[j2]);
  }
  __syncthreads();
  if (tid < 64) {
    float a = 0.f;
    #pragma unroll
    for (int i = 0; i < 32; ++i) {
      float4 w4 = *(const float4*)&f1w[tid*128 + i*4];
      float4 o4 = *(const float4*)&ol[i*4];
      a = fmaf(w4.x, o4.x, a); a = fmaf(w4.y, o4.y, a);
      a = fmaf(w4.z, o4.z, a); a = fmaf(w4.w, o4.w, a);
    }
    f1[tid] = fmaxf(a + f1b[tid], 0.f);
  }
  __syncthreads();
  if (tid == 0) {
    float a = 0.f;
    for (int i = 0; i < 64; ++i) a = fmaf(f2w[i], f1[i], a);
    out[b] = __builtin_amdgcn_rcpf(1.f + __expf(-a));
  }
}

// ---------------------------------------------------------------------------
extern "C" void kernel_launch(void* const* d_in, const int* in_sizes, int n_in,
                              void* d_out, int out_size, void* d_ws, size_t ws_size,
                              hipStream_t stream) {
  (void)in_sizes; (void)n_in; (void)out_size; (void)ws_size;
  const float* x1   = (const float*)d_in[0];
  const float* x2   = (const float*)d_in[1];
  const float* c1w  = (const float*)d_in[2];
  // d_in[3] conv1_b: cancels in BN
  const float* bn1g = (const float*)d_in[4];
  const float* bn1b = (const float*)d_in[5];
  const float* c2w  = (const float*)d_in[6];
  // d_in[7] conv2_b: cancels in BN
  const float* bn2g = (const float*)d_in[8];
  const float* bn2b = (const float*)d_in[9];
  const float* Rw   = (const float*)d_in[10];
  const float* Rb   = (const float*)d_in[11];
  const float* Qw   = (const float*)d_in[12];
  const float* Qb   = (const float*)d_in[13];
  const float* Ow   = (const float*)d_in[14];
  const float* Ob   = (const float*)d_in[15];
  const float* f1w  = (const float*)d_in[16];
  const float* f1b  = (const float*)d_in[17];
  const float* f2w  = (const float*)d_in[18];
  const float* f2b  = (const float*)d_in[19];
  float* outp = (float*)d_out;

  // workspace layout (bytes); total ~50 MB
  char* wsb = (char*)d_ws;
  unsigned short* pool1s = (unsigned short*)wsb;                // 33,554,432 B
  unsigned short* psel2  = (unsigned short*)(wsb + 33554432);   //  8,388,608 B
  float* part1  = (float*)(wsb + 41943040);                     // 524,288 B
  float* part2  = part1 + 131072;                               // 524,288 B
  float* bn1    = part2 + 131072;                               // 512 B
  float* bn2    = bn1 + 128;                                    // 512 B
  unsigned short* wB1 = (unsigned short*)(bn2 + 128);           // 12,288 B
  unsigned short* wB2 = wB1 + 6144;                             // 73,728 B
  unsigned short* qB  = wB2 + 36864;                            // 917,504 B
  float* pqpart = (float*)(qB + 458752);                        // 3,670,016 B (8x1024x112)

  pack_all<<<1960, 256, 0, stream>>>(c1w, c2w, Qw, wB1, wB2, qB);
  conv1_mfma<<<1024, 256, 0, stream>>>(x1, x2, wB1, bn1g, part1, pool1s);
  bn_finalize<<<64, 256, 0, stream>>>(part1, bn1g, bn1b, 1.f/1048576.f, bn1);
  conv2_mfma<<<1024, 256, 0, stream>>>(pool1s, bn1, bn2g, wB2, part2, psel2);
  bn_finalize<<<64, 256, 0, stream>>>(part2, bn2g, bn2b, 1.f/262144.f, bn2);
  preq_mfma<<<dim3(16,8), 256, 0, stream>>>(psel2, bn2, qB, pqpart);
  rnn_head<<<16, 512, 0, stream>>>(pqpart, Qb, Rw, Rb, Qw, Ow, Ob, f1w, f1b, f2w, f2b, outp);
}

// Round 20
// 172.497 us; speedup vs baseline: 1.0449x; 1.0449x over previous
//
#include <hip/hip_runtime.h>
#include <math.h>

// Problem constants
// x: (16,64,3,32,32) x2 concat -> (1024,6,32,32)
// conv1 6->64 k3 p1 -> BN -> ReLU -> pool2 -> (1024,64,16,16)
// conv2 64->64 k3 p1 -> BN -> ReLU -> pool2 -> (1024,64,8,8) = feats (1024,4096)
// RNN T=64 steps over feats rows n=b*64+t ; head -> sigmoid (16,1)
//
// R20 = REVERT to R16 (best measured: 172.4us). R19's reduce-fusion pushed
// 8-way global reads into the latency-critical rnn_head staging (+3us) and
// halved preq's grid to 128 blocks (half GPU idle) -> 180us. R16 config:
// single pooled array per conv (sign(gamma) at producer), 16-way split-K
// preq + separate reduce, R15 rnn_head (77us latency floor).

typedef __attribute__((ext_vector_type(8))) short s8v;   // 8 bf16 (4 VGPRs)
typedef __attribute__((ext_vector_type(4))) float f32x4;

__device__ __forceinline__ unsigned short f2bf(float f) {
  union { float f; unsigned u; } x; x.f = f;
  return (unsigned short)((x.u + 0x7FFFu + ((x.u >> 16) & 1u)) >> 16);  // RNE
}
__device__ __forceinline__ float bf2f(unsigned short u) {
  union { unsigned u; float f; } x; x.u = ((unsigned)u) << 16; return x.f;
}
// fast tanh: 1 - 2/(e^{2x}+1); inf-safe via rcp (e=inf -> 0 -> +1; e->0 -> -1)
__device__ __forceinline__ float ftanh(float x) {
  float e = __expf(2.f * x);
  return 1.f - 2.f * __builtin_amdgcn_rcpf(e + 1.f);
}

// ---------------------------------------------------------------------------
// pack_all: w1 -> bf16 [kh][64co][32k] (k=kw*6+ci, zero pad k>=18);
//           w2 -> bf16 [khw][co][ci] with ci-chunk XOR swizzle;
//           Qw[:, :4096] -> bf16 [112][4096] (rows >=100 zero).
// ---------------------------------------------------------------------------
__global__ __launch_bounds__(256)
void pack_all(const float* __restrict__ w1, const float* __restrict__ w2,
              const float* __restrict__ Qw,
              unsigned short* __restrict__ wB1, unsigned short* __restrict__ wB2,
              unsigned short* __restrict__ qB)
{
  int i = blockIdx.x*256 + threadIdx.x;   // 6144 + 36864 + 458752 = 501760
  if (i < 6144) {
    int kh = i >> 11, rem = i & 2047, co = rem >> 5, k2 = rem & 31;
    unsigned short v = 0;
    if (k2 < 18) {
      int kw = k2 / 6, ci = k2 - 6*kw;
      v = f2bf(w1[co*54 + ci*9 + kh*3 + kw]);
    }
    wB1[i] = v;
  } else if (i < 43008) {
    int j = i - 6144;
    int khw = j >> 12, rem = j & 4095, co = rem >> 6, ci = rem & 63;
    int chunk = (ci >> 3) ^ (co & 7);
    wB2[khw*4096 + co*64 + chunk*8 + (ci & 7)] = f2bf(w2[co*576 + ci*9 + khw]);
  } else if (i < 501760) {
    int j = i - 43008;
    int row = j >> 12, k = j & 4095;
    qB[j] = (row < 100) ? f2bf(Qw[row*4196 + k]) : (unsigned short)0;
  }
}

// ---------------------------------------------------------------------------
// conv1 via MFMA implicit GEMM, computed ONCE. grid 1024, block 256 (4 waves).
// Epilogue stores ONE pooled value per (pixel, channel): max if gamma1>=0
// else min (sign(bn scale) == sign(gamma)).
// ---------------------------------------------------------------------------
__global__ __launch_bounds__(256, 4)
void conv1_mfma(const float* __restrict__ x1, const float* __restrict__ x2,
                const unsigned short* __restrict__ wB1,
                const float* __restrict__ bn1g,
                float* __restrict__ part, unsigned short* __restrict__ pool1s)
{
  __shared__ unsigned xin[3688];          // 34 rows x 108 dwords + 16 pad
  __shared__ float wred[4][4][16][2];
  __shared__ float gsel[64];
  const int n = blockIdx.x, tid = threadIdx.x;
  const int w = tid >> 6, lane = tid & 63;
  const int q = lane >> 4, r = lane & 15;

  if (tid < 64) gsel[tid] = bn1g[tid];

  // B fragments, whole kernel in regs: bf[kh][t], co = 16t + r, k0 = 8q
  s8v bf[3][4];
  #pragma unroll
  for (int kh = 0; kh < 3; ++kh)
    #pragma unroll
    for (int t = 0; t < 4; ++t)
      bf[kh][t] = *(const s8v*)&wB1[kh*2048 + (((t<<4)+r)<<5) + (q<<3)];

  // zero ALL of xin (incl. pad tail) -- overread garbage must be finite
  #pragma unroll
  for (int k = 0; k < 15; ++k) {
    int i = tid + (k<<8);
    if (i < 3688) xin[i] = 0;
  }
  __syncthreads();
  // interior fill: dword (y+1)*108 + (x+1)*3 + cp packs bf16{ci=2cp,2cp+1}
  #pragma unroll
  for (int k = 0; k < 12; ++k) {
    int i = tid + (k<<8);     // 0..3071
    int cp = i >> 10, p = i & 1023;
    int y = p >> 5, x = p & 31;
    float lo, hi;
    if (cp == 0)      { lo = x1[n*3072 + p];        hi = x1[n*3072 + 1024 + p]; }
    else if (cp == 1) { lo = x1[n*3072 + 2048 + p]; hi = x2[n*3072 + p];        }
    else              { lo = x2[n*3072 + 1024 + p]; hi = x2[n*3072 + 2048 + p]; }
    xin[(y+1)*108 + (x+1)*3 + cp] = (unsigned)f2bf(lo) | ((unsigned)f2bf(hi) << 16);
  }
  __syncthreads();

  float st[4], sq[4];
  #pragma unroll
  for (int t = 0; t < 4; ++t) { st[t] = 0.f; sq[t] = 0.f; }
  float pmx[4][2], pmn[4][2];

  #pragma unroll 1
  for (int xb = 0; xb < 2; ++xb) {
    const int xbase = xb << 4;
    #pragma unroll 2
    for (int j = 0; j < 8; ++j) {           // y = 8w + j
      const int y = (w << 3) + j;
      f32x4 acc[4];
      #pragma unroll
      for (int t = 0; t < 4; ++t) acc[t] = (f32x4){0.f,0.f,0.f,0.f};
      #pragma unroll
      for (int kh = 0; kh < 3; ++kh) {      // k-step == kh slice
        int dw = (y + kh)*108 + 3*(xbase + r) + (q << 2);
        union { unsigned u[4]; s8v v; } af;
        af.u[0] = xin[dw];   af.u[1] = xin[dw+1];
        af.u[2] = xin[dw+2]; af.u[3] = xin[dw+3];
        #pragma unroll
        for (int t = 0; t < 4; ++t)
          acc[t] = __builtin_amdgcn_mfma_f32_16x16x32_bf16(af.v, bf[kh][t], acc[t], 0, 0, 0);
      }
      #pragma unroll
      for (int t = 0; t < 4; ++t) {
        st[t] += acc[t][0]+acc[t][1]+acc[t][2]+acc[t][3];
        sq[t] = fmaf(acc[t][0],acc[t][0], fmaf(acc[t][1],acc[t][1],
                fmaf(acc[t][2],acc[t][2], fmaf(acc[t][3],acc[t][3], sq[t]))));
      }
      if ((j & 1) == 0) {                   // even y: stash x-pair max/min
        #pragma unroll
        for (int t = 0; t < 4; ++t) {
          pmx[t][0] = fmaxf(acc[t][0], acc[t][1]); pmx[t][1] = fmaxf(acc[t][2], acc[t][3]);
          pmn[t][0] = fminf(acc[t][0], acc[t][1]); pmn[t][1] = fminf(acc[t][2], acc[t][3]);
        }
      } else {                              // odd y: combine + write pooled sel
        const int py = y >> 1;
        #pragma unroll
        for (int t = 0; t < 4; ++t) {
          int co = (t << 4) + r;
          const bool useMax = (gsel[co] >= 0.f);
          #pragma unroll
          for (int pp = 0; pp < 2; ++pp) {
            float mx = fmaxf(pmx[t][pp], fmaxf(acc[t][2*pp], acc[t][2*pp+1]));
            float mn = fminf(pmn[t][pp], fminf(acc[t][2*pp], acc[t][2*pp+1]));
            int pxp = (xb << 3) + (q << 1) + pp;
            int o = (((n << 8) + (py << 4) + pxp) << 6) + co;
            pool1s[o] = f2bf(useMax ? mx : mn);
          }
        }
      }
    }
  }

  #pragma unroll
  for (int t = 0; t < 4; ++t) {
    float s = st[t], ss = sq[t];
    s  += __shfl_xor(s, 16);  s  += __shfl_xor(s, 32);
    ss += __shfl_xor(ss, 16); ss += __shfl_xor(ss, 32);
    if (q == 0) { wred[w][t][r][0] = s; wred[w][t][r][1] = ss; }
  }
  __syncthreads();
  if (tid < 64) {
    float s = 0.f, ss = 0.f;
    #pragma unroll
    for (int wv = 0; wv < 4; ++wv) {
      s  += wred[wv][tid >> 4][tid & 15][0];
      ss += wred[wv][tid >> 4][tid & 15][1];
    }
    part[tid*2048 + n*2]     = s;     // layout [c][n][2]
    part[tid*2048 + n*2 + 1] = ss;
  }
}

// ---------------------------------------------------------------------------
// BN finalize: per-channel mean/var -> scale/shift.  grid 64, block 256.
// ---------------------------------------------------------------------------
__global__ __launch_bounds__(256)
void bn_finalize(const float* __restrict__ part, const float* __restrict__ g,
                 const float* __restrict__ beta, float inv_cnt, float* __restrict__ bn)
{
  __shared__ float red[8];
  const int c = blockIdx.x, tid = threadIdx.x;
  float s = 0.f, ss = 0.f;
  for (int n = tid; n < 1024; n += 256) {
    s  += part[c*2048 + n*2];
    ss += part[c*2048 + n*2 + 1];
  }
  #pragma unroll
  for (int d = 32; d; d >>= 1) { s += __shfl_xor(s, d); ss += __shfl_xor(ss, d); }
  if ((tid & 63) == 0) { red[(tid>>6)*2] = s; red[(tid>>6)*2+1] = ss; }
  __syncthreads();
  if (tid == 0) {
    float S  = red[0]+red[2]+red[4]+red[6];
    float SS = red[1]+red[3]+red[5]+red[7];
    float m  = S * inv_cnt;
    float var = SS * inv_cnt - m*m;
    float sc = g[c] * rsqrtf(var + 1e-5f);
    bn[c]    = sc;
    bn[64+c] = beta[c] - m*sc;
  }
}

// ---------------------------------------------------------------------------
// conv2 via MFMA implicit GEMM. grid 1024 (one image), block 256 (4 waves).
// Staging fuses conv1 BN affine + ReLU reading the single pool1s array.
// Epilogue stores single pooled sel per channel via sign(gamma2).
// ---------------------------------------------------------------------------
__global__ __launch_bounds__(256)
void conv2_mfma(const unsigned short* __restrict__ pool1s,
                const float* __restrict__ bn1,
                const float* __restrict__ bn2g,
                const unsigned short* __restrict__ wB,
                float* __restrict__ part, unsigned short* __restrict__ psel2)
{
  __shared__ unsigned short xin[324*64];   // 41472 B
  __shared__ unsigned short wL[9*64*64];   // 73728 B
  __shared__ float wred[4][4][16][2];      // 2 KB
  __shared__ float bnL[128];
  __shared__ float g2L[64];
  const int n = blockIdx.x, tid = threadIdx.x;
  const int w = tid >> 6, lane = tid & 63;
  const int q = lane >> 4, col = lane & 15;

  if (tid < 128) bnL[tid] = bn1[tid];
  if (tid >= 128 && tid < 192) g2L[tid - 128] = bn2g[tid - 128];
  // ---- stage weights (linear copy; swizzle pre-applied in pack) ----
  {
    const s8v* src = (const s8v*)wB;
    s8v* dst = (s8v*)wL;
    #pragma unroll
    for (int i = 0; i < 18; ++i) dst[tid + (i<<8)] = src[tid + (i<<8)];
  }
  __syncthreads();   // bnL/g2L ready
  // ---- stage input 18x18x64 bf16 = relu(affine(pool1s)), halo zeros,
  //      swizzled 16B chunks ----
  {
    #pragma unroll
    for (int k = 0; k < 11; ++k) {
      int i = tid + (k<<8);
      if (i < 324*8) {
        int L = i >> 3, s = i & 7;
        int y = L / 18, x = L - y*18;
        s8v v = (s8v){0,0,0,0,0,0,0,0};
        if (y >= 1 && y <= 16 && x >= 1 && x <= 16) {
          int idx = (((n<<8) + ((y-1)<<4) + (x-1))<<6) + (s<<3);
          s8v sv = *(const s8v*)&pool1s[idx];
          #pragma unroll
          for (int e = 0; e < 8; ++e) {
            int ci = (s<<3) + e;
            float sc = bnL[ci], sh = bnL[64+ci];
            float vv = bf2f((unsigned short)sv[e]);
            v[e] = (short)f2bf(fmaxf(fmaf(vv, sc, sh), 0.f));
          }
        }
        *(s8v*)((char*)xin + L*128 + (((s ^ (L & 7)) << 4))) = v;
      }
    }
  }
  __syncthreads();

  f32x4 acc[4][4];   // [mtile][ntile]
  #pragma unroll
  for (int mt = 0; mt < 4; ++mt)
    #pragma unroll
    for (int t = 0; t < 4; ++t)
      acc[mt][t] = (f32x4){0.f,0.f,0.f,0.f};

  const int py0 = w << 2;   // wave's 4 image rows
  #pragma unroll 1
  for (int khw = 0; khw < 9; ++khw) {
    const int kh = khw / 3, kw = khw - 3*kh;
    const char* wslice = (const char*)wL + khw*8192;
    #pragma unroll
    for (int ks = 0; ks < 2; ++ks) {       // ci0 = 32*ks
      const int chunk = (ks << 2) + q;     // 16B-chunk of k within line
      s8v bfrag[4];
      #pragma unroll
      for (int t = 0; t < 4; ++t) {
        int co = (t << 4) + col;
        bfrag[t] = *(const s8v*)(wslice + co*128 + (((chunk ^ (co & 7)) << 4)));
      }
      #pragma unroll
      for (int mt = 0; mt < 4; ++mt) {
        int L = (py0 + mt + kh)*18 + (col + kw);
        s8v afrag = *(const s8v*)((const char*)xin + L*128 + (((chunk ^ (L & 7)) << 4)));
        #pragma unroll
        for (int t = 0; t < 4; ++t)
          acc[mt][t] = __builtin_amdgcn_mfma_f32_16x16x32_bf16(afrag, bfrag[t], acc[mt][t], 0, 0, 0);
      }
    }
  }

  // ---- stats: per-channel sum / sumsq over this block's 256 pixels ----
  #pragma unroll
  for (int t = 0; t < 4; ++t) {
    float s = 0.f, ss = 0.f;
    #pragma unroll
    for (int mt = 0; mt < 4; ++mt)
      #pragma unroll
      for (int r = 0; r < 4; ++r) {
        float v = acc[mt][t][r];
        s += v; ss = fmaf(v, v, ss);
      }
    s  += __shfl_xor(s, 16);  s  += __shfl_xor(s, 32);
    ss += __shfl_xor(ss, 16); ss += __shfl_xor(ss, 32);
    if (q == 0) { wred[w][t][col][0] = s; wred[w][t][col][1] = ss; }
  }
  __syncthreads();
  if (tid < 64) {
    float s = 0.f, ss = 0.f;
    #pragma unroll
    for (int wv = 0; wv < 4; ++wv) {
      s  += wred[wv][tid >> 4][tid & 15][0];
      ss += wred[wv][tid >> 4][tid & 15][1];
    }
    part[tid*2048 + n*2]     = s;
    part[tid*2048 + n*2 + 1] = ss;
  }

  // ---- 2x2 pooled sel (max if gamma2>=0 else min) of raw conv, bf16 ----
  #pragma unroll
  for (int t = 0; t < 4; ++t) {
    int co = (t << 4) + col;
    const bool useMax = (g2L[co] >= 0.f);
    #pragma unroll
    for (int mp = 0; mp < 2; ++mp) {          // vertical pair (rows 2mp,2mp+1)
      f32x4 a0 = acc[2*mp][t], a1 = acc[2*mp+1][t];
      float v0, v1;
      if (useMax) {
        v0 = fmaxf(fmaxf(a0[0], a0[1]), fmaxf(a1[0], a1[1]));
        v1 = fmaxf(fmaxf(a0[2], a0[3]), fmaxf(a1[2], a1[3]));
      } else {
        v0 = fminf(fminf(a0[0], a0[1]), fminf(a1[0], a1[1]));
        v1 = fminf(fminf(a0[2], a0[3]), fminf(a1[2], a1[3]));
      }
      int pyp = (w << 1) + mp;                // pooled y
      int base = ((n*64 + co) << 6) + (pyp << 3) + (q << 1);  // feats c*64+p
      psel2[base] = f2bf(v0); psel2[base+1] = f2bf(v1);
    }
  }
}

// ---------------------------------------------------------------------------
// preQ partials via MFMA, fusing conv2's BN affine + ReLU into the A-frag
// load (single psel2 array). No LDS. grid (16 mblocks x 16 ksplits).
// part layout [ks][1024][112] fp32.
// ---------------------------------------------------------------------------
__global__ __launch_bounds__(256)
void preq_mfma(const unsigned short* __restrict__ psel2,
               const float* __restrict__ bn2,
               const unsigned short* __restrict__ qB,
               float* __restrict__ part)
{
  const int mb = blockIdx.x, ks = blockIdx.y, tid = threadIdx.x;
  const int w = tid >> 6, lane = tid & 63;
  const int q = lane >> 4, col = lane & 15;
  const int m = (mb << 6) + (w << 4) + col;    // A row this lane loads
  const int k00 = ks << 8;

  f32x4 acc[7];
  #pragma unroll
  for (int t = 0; t < 7; ++t) acc[t] = (f32x4){0.f,0.f,0.f,0.f};

  #pragma unroll 2
  for (int kk = 0; kk < 8; ++kk) {
    const int k = k00 + (kk << 5) + (q << 3);  // 8-aligned, one c per chunk
    const int c = k >> 6;
    const float sc = bn2[c], sh = bn2[64 + c];
    s8v sv = *(const s8v*)&psel2[m*4096 + k];
    s8v a;
    #pragma unroll
    for (int e = 0; e < 8; ++e)
      a[e] = (short)f2bf(fmaxf(fmaf(bf2f((unsigned short)sv[e]), sc, sh), 0.f));
    #pragma unroll
    for (int t = 0; t < 7; ++t) {
      s8v bb = *(const s8v*)&qB[(((t << 4) + col) << 12) + k];
      acc[t] = __builtin_amdgcn_mfma_f32_16x16x32_bf16(a, bb, acc[t], 0, 0, 0);
    }
  }

  // C: col=lane&15 = j16, row=4q+r = m-row within the wave's 16-row tile
  float* dst = part + ks*114688 + ((mb << 6) + (w << 4) + (q << 2))*112;
  #pragma unroll
  for (int t = 0; t < 7; ++t)
    #pragma unroll
    for (int r = 0; r < 4; ++r)
      dst[r*112 + (t << 4) + col] = acc[t][r];
}

// preQ[n][100] = sum_ks part[ks][n][j] + Qb[j].  grid 400, block 256.
__global__ __launch_bounds__(256)
void preq_reduce(const float* __restrict__ part, const float* __restrict__ Qb,
                 float* __restrict__ preQ)
{
  int idx = blockIdx.x*256 + threadIdx.x;  // 102400 exact
  if (idx < 1024*100) {
    int n = idx / 100, j = idx - n*100;
    float s = Qb[j];
    #pragma unroll
    for (int ks = 0; ks < 16; ++ks) s += part[ks*114688 + n*112 + j];
    preQ[idx] = s;
  }
}

// ---------------------------------------------------------------------------
// RNN (64 sequential steps) + head. grid 16 (one block per batch b), block 512.
// R15 structure: Q-phase fuses Ha update (2 barriers/step); Ha element in a
// register with write-through; rt padded 4x28 for b128 reads; ftanh.
// ---------------------------------------------------------------------------
__global__ __launch_bounds__(512, 2)
void rnn_head(const float* __restrict__ preQ, const float* __restrict__ Rw,
              const float* __restrict__ Rb, const float* __restrict__ Qw,
              const float* __restrict__ Ow, const float* __restrict__ Ob,
              const float* __restrict__ f1w, const float* __restrict__ f1b,
              const float* __restrict__ f2w, const float* __restrict__ f2b,
              float* __restrict__ out)
{
  __shared__ __align__(16) float ha[400];
  __shared__ __align__(16) float rtP[112];   // 4 quarters x 28 (pads zero)
  __shared__ float pq[6400];
  __shared__ float rb[100];
  __shared__ __align__(16) float ol[128];
  __shared__ float f1[64];
  const int b = blockIdx.x, tid = threadIdx.x;

  for (int i = tid; i < 6400; i += 512) pq[i] = preQ[b*6400 + i];
  if (tid < 100) rb[tid] = Rb[tid];
  if (tid < 400) ha[tid] = 0.f;
  if (tid < 112) rtP[tid] = 0.f;             // pads stay zero forever

  const int o = tid >> 2, q4 = tid & 3;
  const int rtSlot = (o / 25)*28 + (o % 25);
  float rw[100], qw[28];
  if (tid < 400) {
    const float* rsrc = &Rw[o*400 + q4*100];
    #pragma unroll
    for (int i = 0; i < 25; ++i) {
      float4 v = *(const float4*)&rsrc[i*4];
      rw[i*4] = v.x; rw[i*4+1] = v.y; rw[i*4+2] = v.z; rw[i*4+3] = v.w;
    }
    const float* qsrc = &Qw[o*4196 + 4096 + q4*25];
    #pragma unroll
    for (int i = 0; i < 25; ++i) qw[i] = qsrc[i];
    qw[25] = 0.f; qw[26] = 0.f; qw[27] = 0.f;   // multiply rtP pads
  }
  const float Aa = (q4==0) ? 0.f : (q4==1) ? 0.25f : (q4==2) ? 0.5f : 0.95f;
  const float Ba = 1.f - Aa;
  float haReg = 0.f;
  __syncthreads();

  for (int t = 0; t < 64; ++t) {
    if (tid < 400) {
      float r0 = 0.f, r1 = 0.f, r2 = 0.f, r3 = 0.f;
      const float* hp = &ha[q4*100];
      #pragma unroll
      for (int i = 0; i < 25; i += 4) {
        float4 a0 = *(const float4*)&hp[i*4];
        float4 a1 = *(const float4*)&hp[i*4+4];
        float4 a2 = *(const float4*)&hp[i*4+8];
        float4 a3 = *(const float4*)&hp[i*4+12];
        r0 = fmaf(rw[i*4],    a0.x, r0); r0 = fmaf(rw[i*4+1],  a0.y, r0);
        r0 = fmaf(rw[i*4+2],  a0.z, r0); r0 = fmaf(rw[i*4+3],  a0.w, r0);
        if (i+1 < 25) {
          r1 = fmaf(rw[i*4+4],  a1.x, r1); r1 = fmaf(rw[i*4+5],  a1.y, r1);
          r1 = fmaf(rw[i*4+6],  a1.z, r1); r1 = fmaf(rw[i*4+7],  a1.w, r1);
        }
        if (i+2 < 25) {
          r2 = fmaf(rw[i*4+8],  a2.x, r2); r2 = fmaf(rw[i*4+9],  a2.y, r2);
          r2 = fmaf(rw[i*4+10], a2.z, r2); r2 = fmaf(rw[i*4+11], a2.w, r2);
        }
        if (i+3 < 25) {
          r3 = fmaf(rw[i*4+12], a3.x, r3); r3 = fmaf(rw[i*4+13], a3.y, r3);
          r3 = fmaf(rw[i*4+14], a3.z, r3); r3 = fmaf(rw[i*4+15], a3.w, r3);
        }
      }
      float racc = (r0 + r1) + (r2 + r3);
      racc += __shfl_xor(racc, 1);
      racc += __shfl_xor(racc, 2);
      if (q4 == 0) rtP[rtSlot] = ftanh(racc + rb[o]);
    }
    __syncthreads();
    if (tid < 400) {
      float s0 = 0.f, s1 = 0.f;
      const float* rp = &rtP[q4*28];
      #pragma unroll
      for (int i = 0; i < 7; i += 2) {
        float4 v0 = *(const float4*)&rp[i*4];
        s0 = fmaf(qw[i*4],   v0.x, s0); s0 = fmaf(qw[i*4+1], v0.y, s0);
        s0 = fmaf(qw[i*4+2], v0.z, s0); s0 = fmaf(qw[i*4+3], v0.w, s0);
        if (i+1 < 7) {
          float4 v1 = *(const float4*)&rp[i*4+4];
          s1 = fmaf(qw[i*4+4], v1.x, s1); s1 = fmaf(qw[i*4+5], v1.y, s1);
          s1 = fmaf(qw[i*4+6], v1.z, s1); s1 = fmaf(qw[i*4+7], v1.w, s1);
        }
      }
      float qacc = s0 + s1;
      qacc += __shfl_xor(qacc, 1);
      qacc += __shfl_xor(qacc, 2);
      float qt = ftanh(qacc + pq[t*100 + o]);
      haReg = fmaf(Aa, haReg, Ba*qt);
      ha[q4*100 + o] = haReg;           // write-through for next R-phase
    }
    __syncthreads();
  }

  // head: out_last = tanh(Hf @ Ow^T + Ob), 2 threads per output
  if (tid < 256) {
    const int j2 = tid >> 1, hh = tid & 1;
    const float* osrc = &Ow[j2*400 + hh*200];
    const float* hp = &ha[hh*200];
    float oacc = 0.f;
    #pragma unroll
    for (int i = 0; i < 50; ++i) {
      float4 w4 = *(const float4*)&osrc[i*4];
      float4 h4 = *(const float4*)&hp[i*4];
      oacc = fmaf(w4.x, h4.x, oacc); oacc = fmaf(w4.y, h4.y, oacc);
      oacc = fmaf(w4.z, h4.z, oacc); oacc = fmaf(w4.w, h4.w, oacc);
    }
    oacc += __shfl_xor(oacc, 1);
    if (hh == 0) ol[j2] = ftanh(oacc + Ob[j2]);
  }
  __syncthreads();
  if (tid < 64) {
    float a = 0.f;
    #pragma unroll
    for (int i = 0; i < 32; ++i) {
      float4 w4 = *(const float4*)&f1w[tid*128 + i*4];
      float4 o4 = *(const float4*)&ol[i*4];
      a = fmaf(w4.x, o4.x, a); a = fmaf(w4.y, o4.y, a);
      a = fmaf(w4.z, o4.z, a); a = fmaf(w4.w, o4.w, a);
    }
    f1[tid] = fmaxf(a + f1b[tid], 0.f);
  }
  __syncthreads();
  if (tid == 0) {
    float a = 0.f;
    for (int i = 0; i < 64; ++i) a = fmaf(f2w[i], f1[i], a);
    out[b] = __builtin_amdgcn_rcpf(1.f + __expf(-a));
  }
}

// ---------------------------------------------------------------------------
extern "C" void kernel_launch(void* const* d_in, const int* in_sizes, int n_in,
                              void* d_out, int out_size, void* d_ws, size_t ws_size,
                              hipStream_t stream) {
  (void)in_sizes; (void)n_in; (void)out_size; (void)ws_size;
  const float* x1   = (const float*)d_in[0];
  const float* x2   = (const float*)d_in[1];
  const float* c1w  = (const float*)d_in[2];
  // d_in[3] conv1_b: cancels in BN
  const float* bn1g = (const float*)d_in[4];
  const float* bn1b = (const float*)d_in[5];
  const float* c2w  = (const float*)d_in[6];
  // d_in[7] conv2_b: cancels in BN
  const float* bn2g = (const float*)d_in[8];
  const float* bn2b = (const float*)d_in[9];
  const float* Rw   = (const float*)d_in[10];
  const float* Rb   = (const float*)d_in[11];
  const float* Qw   = (const float*)d_in[12];
  const float* Qb   = (const float*)d_in[13];
  const float* Ow   = (const float*)d_in[14];
  const float* Ob   = (const float*)d_in[15];
  const float* f1w  = (const float*)d_in[16];
  const float* f1b  = (const float*)d_in[17];
  const float* f2w  = (const float*)d_in[18];
  const float* f2b  = (const float*)d_in[19];
  float* outp = (float*)d_out;

  // workspace layout (bytes); total ~60 MB
  char* wsb = (char*)d_ws;
  unsigned short* pool1s = (unsigned short*)wsb;                // 33,554,432 B
  unsigned short* psel2  = (unsigned short*)(wsb + 33554432);   //  8,388,608 B
  float* part1  = (float*)(wsb + 41943040);                     // 524,288 B
  float* part2  = part1 + 131072;                               // 524,288 B
  float* bn1    = part2 + 131072;                               // 512 B
  float* bn2    = bn1 + 128;                                    // 512 B
  float* preQ   = bn2 + 128;                                    // 409,600 B
  unsigned short* wB1 = (unsigned short*)(preQ + 102400);       // 12,288 B
  unsigned short* wB2 = wB1 + 6144;                             // 73,728 B
  unsigned short* qB  = wB2 + 36864;                            // 917,504 B
  float* pqpart = (float*)(qB + 458752);                        // 7,340,032 B

  pack_all<<<1960, 256, 0, stream>>>(c1w, c2w, Qw, wB1, wB2, qB);
  conv1_mfma<<<1024, 256, 0, stream>>>(x1, x2, wB1, bn1g, part1, pool1s);
  bn_finalize<<<64, 256, 0, stream>>>(part1, bn1g, bn1b, 1.f/1048576.f, bn1);
  conv2_mfma<<<1024, 256, 0, stream>>>(pool1s, bn1, bn2g, wB2, part2, psel2);
  bn_finalize<<<64, 256, 0, stream>>>(part2, bn2g, bn2b, 1.f/262144.f, bn2);
  preq_mfma<<<dim3(16,16), 256, 0, stream>>>(psel2, bn2, qB, pqpart);
  preq_reduce<<<400, 256, 0, stream>>>(pqpart, Qb, preQ);
  rnn_head<<<16, 512, 0, stream>>>(preQ, Rw, Rb, Qw, Ow, Ob, f1w, f1b, f2w, f2b, outp);
}